// Round 10
// baseline (409.355 us; speedup 1.0000x reference)
//
#include <hip/hip_runtime.h>
#include <hip/hip_bf16.h>
#include <hip/hip_fp16.h>
#include <math.h>

#define MAXDEG 512

typedef short v8s __attribute__((ext_vector_type(8)));
typedef float v4f __attribute__((ext_vector_type(4)));
typedef _Float16 h2 __attribute__((ext_vector_type(2)));

// ---------------- block reduce helpers ----------------
__device__ __forceinline__ float blockReduceSum(float v) {
    __shared__ float sh[8];
    int lane = threadIdx.x & 63, w = threadIdx.x >> 6;
    for (int o = 32; o > 0; o >>= 1) v += __shfl_down(v, o);
    __syncthreads();
    if (lane == 0) sh[w] = v;
    __syncthreads();
    if (w == 0) {
        int nw = (blockDim.x + 63) >> 6;
        v = (lane < nw) ? sh[lane] : 0.f;
        for (int o = 4; o > 0; o >>= 1) v += __shfl_down(v, o);
        if (lane == 0) sh[0] = v;
    }
    __syncthreads();
    return sh[0];
}

__device__ __forceinline__ float blockReduceMax(float v) {
    __shared__ float sh[8];
    int lane = threadIdx.x & 63, w = threadIdx.x >> 6;
    for (int o = 32; o > 0; o >>= 1) v = fmaxf(v, __shfl_down(v, o));
    __syncthreads();
    if (lane == 0) sh[w] = v;
    __syncthreads();
    if (w == 0) {
        int nw = (blockDim.x + 63) >> 6;
        v = (lane < nw) ? sh[lane] : -3.4e38f;
        for (int o = 4; o > 0; o >>= 1) v = fmaxf(v, __shfl_down(v, o));
        if (lane == 0) sh[0] = v;
    }
    __syncthreads();
    return sh[0];
}

__device__ __forceinline__ float leaky(float x) { return x >= 0.f ? x : 0.2f * x; }

// ---------------- kernels ----------------

// Fused: blocks [0,4096) do CSR build (batched LDS atomics) + s_mat row sums;
// remaining blocks do hin conversion, weight transposes (fp16), el/er zeroing.
__global__ void fused_pre(const float* __restrict__ adj, const float* __restrict__ s,
                          int* __restrict__ colIdx, int* __restrict__ deg,
                          float* __restrict__ dv,
                          const float* __restrict__ x, const int* __restrict__ obs,
                          const float* __restrict__ theta,
                          const float* __restrict__ Wh0, const float* __restrict__ Wh1,
                          const float* __restrict__ Wo0,
                          __half* __restrict__ hin, __half* __restrict__ Wh0t,
                          __half* __restrict__ Wh1t, __half* __restrict__ Wo0t,
                          float* __restrict__ elerZ, int elerN, int N) {
    if (blockIdx.x < 4096) {
        int row = blockIdx.x;
        __shared__ int cnt;
        if (threadIdx.x == 0) cnt = 0;
        __syncthreads();
        const float4* ar = (const float4*)(adj + (size_t)row * N);
        const float4* sr = (const float4*)(s + (size_t)row * N);
        int* outp = colIdx + (size_t)row * MAXDEG;
        float psum = 0.f;
        const int n4 = N >> 2;
        for (int j4 = threadIdx.x; j4 < n4; j4 += blockDim.x) {
            float4 a4 = ar[j4];
            float4 s4 = sr[j4];
            psum += (s4.x + s4.y) + (s4.z + s4.w);
            int jb = j4 << 2;
            int idx[4];
            int c4 = 0;
            if (a4.x > 0.f) idx[c4++] = jb;
            if (a4.y > 0.f) idx[c4++] = jb + 1;
            if (a4.z > 0.f) idx[c4++] = jb + 2;
            if (a4.w > 0.f) idx[c4++] = jb + 3;
            if (c4) {
                int p = atomicAdd(&cnt, c4);
                #pragma unroll
                for (int t = 0; t < 4; t++)
                    if (t < c4 && p + t < MAXDEG) outp[p + t] = idx[t];
            }
        }
        psum = blockReduceSum(psum);
        __syncthreads();
        if (threadIdx.x == 0) {
            deg[row] = cnt < MAXDEG ? cnt : MAXDEG;
            dv[row] = psum;
        }
        return;
    }
    const int n0 = 4096 * 512;       // hin
    const int n1 = 4 * 512 * 256;    // Wh0t
    const int n2 = 4 * 256 * 256;    // Wh1t
    const int n3 = 1024 * 64;        // Wo0t
    int i = (blockIdx.x - 4096) * 256 + threadIdx.x;
    if (i < n0) {
        int n = i >> 9, f = i & 511;
        float v = x[i];
        if (obs[n] == 1) v += theta[f];
        hin[i] = __float2half(v);
    } else if (i < n0 + n1) {
        int t = i - n0;                         // [b][m<256][k<512]
        int b = t / (512 * 256), r = t % (512 * 256);
        int mm = r >> 9, kk = r & 511;
        Wh0t[t] = __float2half(Wh0[b * 512 * 256 + kk * 256 + mm]);
    } else if (i < n0 + n1 + n2) {
        int t = i - n0 - n1;                    // [b][m<256][k<256]
        int b = t >> 16, r = t & 65535;
        int mm = r >> 8, kk = r & 255;
        Wh1t[t] = __float2half(Wh1[b * 65536 + kk * 256 + mm]);
    } else if (i < n0 + n1 + n2 + n3) {
        int t = i - n0 - n1 - n2;               // [m<64][k<1024]
        int mm = t >> 10, kk = t & 1023;
        Wo0t[t] = __float2half(Wo0[kk * 64 + mm]);
    } else if (i < n0 + n1 + n2 + n3 + elerN) {
        elerZ[i - n0 - n1 - n2 - n3] = 0.f;
    }
}

// 64x64 tile batched GEMM (fp16 in/out), fused el/er epilogue.
// 4 blocks/CU at this grid size -> inter-block latency hiding.
__global__ __launch_bounds__(256) void gemm_mfma64(
    const __half* __restrict__ A, const __half* __restrict__ Bt,
    __half* __restrict__ C, int N, int K, int M,
    size_t sA, size_t sB, size_t sC,
    const float* __restrict__ aVec, size_t aStride,
    float* __restrict__ el, float* __restrict__ er) {
    int b = blockIdx.z;
    const unsigned short* Ag = (const unsigned short*)(A + (size_t)b * sA);
    const unsigned short* Bg = (const unsigned short*)(Bt + (size_t)b * sB);
    __half* Cg = C + (size_t)b * sC;
    const float* av = aVec + (size_t)b * aStride;

    __shared__ __align__(16) unsigned short As[64][40];
    __shared__ __align__(16) unsigned short Bs[64][40];

    const int tid = threadIdx.x;
    const int wave = tid >> 6, lane = tid & 63;
    const int row0 = blockIdx.y * 64, col0 = blockIdx.x * 64;
    const int sRow = tid >> 2;
    const int sOff = (tid & 3) * 8;
    const int m = lane & 15, quad = lane >> 4;

    v4f acc[4];
    #pragma unroll
    for (int c = 0; c < 4; c++) acc[c] = (v4f)(0.f);

    for (int k0 = 0; k0 < K; k0 += 32) {
        *(int4*)(&As[sRow][sOff]) =
            *(const int4*)(Ag + (size_t)(row0 + sRow) * K + k0 + sOff);
        *(int4*)(&Bs[sRow][sOff]) =
            *(const int4*)(Bg + (size_t)(col0 + sRow) * K + k0 + sOff);
        __syncthreads();
        v8s af = *(const v8s*)(&As[wave * 16 + m][quad * 8]);
        #pragma unroll
        for (int c = 0; c < 4; c++) {
            v8s bfv = *(const v8s*)(&Bs[c * 16 + m][quad * 8]);
            acc[c] = __builtin_amdgcn_mfma_f32_16x16x32_f16(af, bfv, acc[c], 0, 0, 0);
        }
        __syncthreads();
    }
    #pragma unroll
    for (int c = 0; c < 4; c++)
        #pragma unroll
        for (int r = 0; r < 4; r++) {
            int row = row0 + wave * 16 + quad * 4 + r;
            int col = col0 + c * 16 + m;
            Cg[(size_t)row * M + col] = __float2half(acc[c][r]);
        }
    float ael[4], aer[4];
    #pragma unroll
    for (int c = 0; c < 4; c++) {
        ael[c] = av[col0 + c * 16 + m];
        aer[c] = av[M + col0 + c * 16 + m];
    }
    #pragma unroll
    for (int r = 0; r < 4; r++) {
        float pel = 0.f, per_ = 0.f;
        #pragma unroll
        for (int c = 0; c < 4; c++) {
            pel += acc[c][r] * ael[c];
            per_ += acc[c][r] * aer[c];
        }
        #pragma unroll
        for (int off = 1; off < 16; off <<= 1) {
            pel += __shfl_xor(pel, off);
            per_ += __shfl_xor(per_, off);
        }
        if (m == 0) {
            int row = row0 + wave * 16 + quad * 4 + r;
            atomicAdd(&el[(size_t)b * N + row], pel);
            atomicAdd(&er[(size_t)b * N + row], per_);
        }
    }
}

// Masked softmax + fp16 gather. UNROLL adjacent neighbors per sub per iter;
// UNROLL/2 ds_read_b128 for spc; UNROLL outstanding uint4 global loads.
// FUSE=1 (D=64): dot the result with Wo1 -> o2wh/el4/er4 instead of storing.
template<int D, int ACT, int HEADS, int FUSE, int UNROLL>
__global__ __launch_bounds__(256) void attn_vec(
    const __half* __restrict__ Wh, const float* __restrict__ el,
    const float* __restrict__ er, const int* __restrict__ colIdx,
    const int* __restrict__ deg, __half* __restrict__ out,
    int N, size_t sWh, size_t sOut, int outRowStride,
    const float* __restrict__ wo1, const float* __restrict__ ao1,
    float* __restrict__ o2wh, float* __restrict__ el4, float* __restrict__ er4) {
    constexpr int LPN = D / 8;              // lanes per neighbor (8 fp16/lane)
    constexpr int SUBS = 64 / LPN;          // sub-groups per wave
    constexpr int PER_WAVE = SUBS * UNROLL; // neighbors per wave per iteration
    constexpr int PAD = 4 * PER_WAVE;       // neighbors per block per iteration

    int b, row;
    if (HEADS == 4) {
        int blk = blockIdx.x;
        b = (blk & 7) >> 1;
        row = ((blk >> 3) << 1) | (blk & 1);
    } else {
        b = 0;
        row = blockIdx.x;
    }
    const int tid = threadIdx.x;
    const __half* whb = Wh + (size_t)b * sWh;
    const float* erb = er + (size_t)b * N;
    const float eln = el[(size_t)b * N + row];
    const int dc = deg[row];
    const int dcp = (dc + PAD - 1) & ~(PAD - 1);
    const int* ci = colIdx + (size_t)row * MAXDEG;

    __shared__ __align__(16) float2 spc[MAXDEG];  // {packed half2 p, byte off}
    __shared__ __align__(16) float redc[4 * D];

    float mx = -3.4e38f;
    for (int k = tid; k < dc; k += 256) {
        int j = ci[k];
        float s = eln + erb[j];
        s = fmaxf(s, 0.2f * s);               // LeakyReLU(0.2)
        spc[k] = make_float2(s, __int_as_float(j * (D * 2)));
        mx = fmaxf(mx, s);
    }
    for (int k = dc + tid; k < dcp; k += 256)
        spc[k] = make_float2(__int_as_float(0), __int_as_float(0));
    mx = blockReduceMax(mx);
    float l = 0.f;
    for (int k = tid; k < dc; k += 256) {
        float p = __expf(spc[k].x - mx);
        l += p;
        unsigned int pu = __half_as_ushort(__float2half(p));
        spc[k].x = __int_as_float(pu | (pu << 16));   // packed half2 {p,p}
    }
    l = blockReduceSum(l);
    const float inv = 1.f / l;

    const int wave = tid >> 6, lane = tid & 63;
    const int sub = lane / LPN;
    const int dl = (lane % LPN) * 8;
    const char* wp = (const char*)(whb + dl);

    union HU { unsigned int u; h2 h; };
    union R4 { uint4 u; h2 h[4]; };

    h2 a0[4], a1[4];
    #pragma unroll
    for (int i = 0; i < 4; i++) { a0[i] = (h2)(_Float16)0; a1[i] = (h2)(_Float16)0; }

    for (int k = wave * PER_WAVE + sub * UNROLL; k < dcp; k += PAD) {
        float4 pq[UNROLL / 2];
        #pragma unroll
        for (int u = 0; u < UNROLL / 2; u++)
            pq[u] = *(const float4*)(&spc[k + 2 * u]);
        R4 r[UNROLL];
        #pragma unroll
        for (int u = 0; u < UNROLL / 2; u++) {
            r[2 * u].u     = *(const uint4*)(wp + __float_as_int(pq[u].y));
            r[2 * u + 1].u = *(const uint4*)(wp + __float_as_int(pq[u].w));
        }
        #pragma unroll
        for (int u = 0; u < UNROLL / 2; u++) {
            HU pa, pb;
            pa.u = __float_as_int(pq[u].x);
            pb.u = __float_as_int(pq[u].z);
            #pragma unroll
            for (int i = 0; i < 4; i++) {
                a0[i] += pa.h * r[2 * u].h[i];
                a1[i] += pb.h * r[2 * u + 1].h[i];
            }
        }
    }
    #pragma unroll
    for (int i = 0; i < 4; i++) a0[i] += a1[i];
    // cross-sub-group reduce on packed halves
    #pragma unroll
    for (int off = LPN; off < 64; off <<= 1)
        #pragma unroll
        for (int i = 0; i < 4; i++) {
            HU t, s;
            t.h = a0[i];
            s.u = __shfl_xor((int)t.u, off);
            a0[i] += s.h;
        }
    __syncthreads();
    if (sub == 0)
        #pragma unroll
        for (int i = 0; i < 4; i++) {
            redc[wave * D + dl + 2 * i]     = (float)a0[i][0];
            redc[wave * D + dl + 2 * i + 1] = (float)a0[i][1];
        }
    __syncthreads();
    if (FUSE) {
        if (tid < 64) {
            float vv = (redc[tid] + redc[D + tid] + redc[2 * D + tid] + redc[3 * D + tid]) * inv;
            float t = vv * wo1[tid];
            #pragma unroll
            for (int o = 32; o > 0; o >>= 1) t += __shfl_down(t, o);
            if (tid == 0) {
                o2wh[row] = t;
                el4[row] = t * ao1[0];
                er4[row] = t * ao1[1];
            }
        }
        return;
    }
    if (tid < D) {
        float v = (redc[tid] + redc[D + tid] + redc[2 * D + tid] + redc[3 * D + tid]) * inv;
        if (ACT == 1) v = (v > 0.f) ? v : expm1f(v);   // ELU
        out[(size_t)b * sOut + (size_t)row * outRowStride + tid] = __float2half(v);
    }
}

// D==1 attention + elu + degreeNN fused (one block per row).
__global__ void attn_d1_deg(const float* __restrict__ o2wh, const float* __restrict__ el,
                            const float* __restrict__ er, const int* __restrict__ colIdx,
                            const int* __restrict__ deg, const float* __restrict__ dv,
                            const float* __restrict__ dW, const float* __restrict__ dW0,
                            const float* __restrict__ dW1, const float* __restrict__ dW01,
                            const float* __restrict__ dW2, const float* __restrict__ dW02,
                            const float* __restrict__ dV, const float* __restrict__ dV0,
                            float* __restrict__ out, int N) {
    int row = blockIdx.x, tid = threadIdx.x;
    const float eln = el[row];
    const int dc = deg[row];
    const int* ci = colIdx + (size_t)row * MAXDEG;
    __shared__ float sp[MAXDEG];
    __shared__ int sc[MAXDEG];
    float mx = -3.4e38f;
    for (int k = tid; k < dc; k += blockDim.x) {
        int j = ci[k];
        sc[k] = j;
        float s = eln + er[j];
        s = fmaxf(s, 0.2f * s);
        sp[k] = s;
        mx = fmaxf(mx, s);
    }
    mx = blockReduceMax(mx);
    float l = 0.f, acc = 0.f;
    for (int k = tid; k < dc; k += blockDim.x) {
        float p = __expf(sp[k] - mx);
        l += p;
        acc += p * o2wh[sc[k]];
    }
    l = blockReduceSum(l);
    acc = blockReduceSum(acc);
    if (tid == 0) {
        float h = acc / l;
        h = (h > 0.f) ? h : expm1f(h);            // elu
        float d = dv[row];
        float t0[10], t1[20], t2[10];
        #pragma unroll
        for (int i = 0; i < 10; i++)
            t0[i] = leaky(h * dW[i] + d * dW[10 + i] + dW0[i]);
        #pragma unroll
        for (int j = 0; j < 20; j++) {
            float s = dW01[j];
            #pragma unroll
            for (int i = 0; i < 10; i++) s += t0[i] * dW1[i * 20 + j];
            t1[j] = leaky(s);
        }
        #pragma unroll
        for (int j = 0; j < 10; j++) {
            float s = dW02[j];
            #pragma unroll
            for (int i = 0; i < 20; i++) s += t1[i] * dW2[i * 10 + j];
            t2[j] = leaky(s);
        }
        float o = dV0[0];
        #pragma unroll
        for (int i = 0; i < 10; i++) o += t2[i] * dV[i];
        out[row] = leaky(o);
    }
}

// ---------------- launch ----------------
extern "C" void kernel_launch(void* const* d_in, const int* in_sizes, int n_in,
                              void* d_out, int out_size, void* d_ws, size_t ws_size,
                              hipStream_t stream) {
    const int N = 4096, F = 512, H = 4, D1 = 256, O1 = 64;
    const float* x     = (const float*)d_in[0];
    const float* adj   = (const float*)d_in[1];
    const int*   obs   = (const int*)  d_in[2];
    const float* s_mat = (const float*)d_in[3];
    const float* theta = (const float*)d_in[4];
    const float* Wh0   = (const float*)d_in[5];
    const float* ah0   = (const float*)d_in[6];
    const float* Wh1   = (const float*)d_in[7];
    const float* ah1   = (const float*)d_in[8];
    const float* Wo0   = (const float*)d_in[9];
    const float* ao0   = (const float*)d_in[10];
    const float* Wo1   = (const float*)d_in[11];
    const float* ao1   = (const float*)d_in[12];
    const float* dWp   = (const float*)d_in[13];
    const float* dW0p  = (const float*)d_in[14];
    const float* dW1p  = (const float*)d_in[15];
    const float* dW01p = (const float*)d_in[16];
    const float* dW2p  = (const float*)d_in[17];
    const float* dW02p = (const float*)d_in[18];
    const float* dVp   = (const float*)d_in[19];
    const float* dV0p  = (const float*)d_in[20];
    float* outp = (float*)d_out;

    char* ws = (char*)d_ws;
    auto alloc = [&](size_t bytes) {
        char* p = ws;
        ws += (bytes + 255) & ~(size_t)255;
        return p;
    };
    __half* hin  = (__half*)alloc((size_t)N * F * 2);
    __half* whA  = (__half*)alloc((size_t)H * N * D1 * 2);
    __half* hb   = (__half*)alloc((size_t)H * N * D1 * 2);
    __half* hcat = (__half*)alloc((size_t)N * H * D1 * 2);
    __half* o1Wh = (__half*)alloc((size_t)N * O1 * 2);
    float* o2Wh  = (float*)alloc((size_t)N * 4);
    __half* Wh0t = (__half*)alloc((size_t)H * F * D1 * 2);
    __half* Wh1t = (__half*)alloc((size_t)H * D1 * D1 * 2);
    __half* Wo0t = (__half*)alloc((size_t)H * D1 * O1 * 2);
    int elerN = 4 * H * N + 2 * N;
    float* elerZ = (float*)alloc((size_t)elerN * 4);
    float* el1 = elerZ;
    float* er1 = el1 + H * N;
    float* el2 = er1 + H * N;
    float* er2 = el2 + H * N;
    float* el3 = er2 + H * N;
    float* er3 = el3 + N;
    float* el4 = (float*)alloc((size_t)N * 4);
    float* er4 = (float*)alloc((size_t)N * 4);
    float* dv  = (float*)alloc((size_t)N * 4);
    int* colIdx = (int*)alloc((size_t)N * MAXDEG * 4);
    int* deg    = (int*)alloc((size_t)N * 4);

    {
        const int totalPrep = N * F + H * F * D1 + H * D1 * D1 + H * D1 * O1 + elerN;
        const int prepBlocks = (totalPrep + 255) / 256;
        fused_pre<<<4096 + prepBlocks, 256, 0, stream>>>(
            adj, s_mat, colIdx, deg, dv,
            x, obs, theta, Wh0, Wh1, Wo0, hin, Wh0t, Wh1t, Wo0t, elerZ, elerN, N);
    }

    // ----- multi-head layer 1 (D=256, elu) -----
    gemm_mfma64<<<dim3(D1 / 64, N / 64, H), 256, 0, stream>>>(
        hin, Wh0t, whA, N, F, D1, 0, (size_t)D1 * F, (size_t)N * D1,
        ah0, (size_t)2 * D1, el1, er1);
    attn_vec<256, 1, 4, 0, 8><<<N * H, 256, 0, stream>>>(
        whA, el1, er1, colIdx, deg, hb,
        N, (size_t)N * D1, (size_t)N * D1, D1,
        nullptr, nullptr, nullptr, nullptr, nullptr);

    // ----- multi-head layer 2 (D=256, elu) -> hcat interleaved -----
    gemm_mfma64<<<dim3(D1 / 64, N / 64, H), 256, 0, stream>>>(
        hb, Wh1t, whA, N, D1, D1, (size_t)N * D1, (size_t)D1 * D1, (size_t)N * D1,
        ah1, (size_t)2 * D1, el2, er2);
    attn_vec<256, 1, 4, 0, 8><<<N * H, 256, 0, stream>>>(
        whA, el2, er2, colIdx, deg, hcat,
        N, (size_t)N * D1, (size_t)D1, H * D1,
        nullptr, nullptr, nullptr, nullptr, nullptr);

    // ----- output layer 1 (D=64, no act) + fused matvec (Wo1) -----
    gemm_mfma64<<<dim3(O1 / 64, N / 64, 1), 256, 0, stream>>>(
        hcat, Wo0t, o1Wh, N, H * D1, O1, 0, 0, 0,
        ao0, 0, el3, er3);
    attn_vec<64, 0, 1, 1, 4><<<N, 256, 0, stream>>>(
        o1Wh, el3, er3, colIdx, deg, nullptr,
        N, 0, 0, O1,
        Wo1, ao1, o2Wh, el4, er4);

    // ----- output layer 2 (D=1) + elu + degreeNN -----
    attn_d1_deg<<<N, 256, 0, stream>>>(o2Wh, el4, er4, colIdx, deg, dv,
        dWp, dW0p, dW1p, dW01p, dW2p, dW02p, dVp, dV0p, outp, N);
}